// Round 13
// baseline (457.883 us; speedup 1.0000x reference)
//
#include <hip/hip_runtime.h>
#include <hip/hip_fp8.h>
#include <cstdint>
#include <cstddef>

// ---------------------------------------------------------------------------
// GAT link predictor, round 13.
//  - Round-12 falsified bytes-bound theory (fp8 halved FETCH, time flat).
//    Counters show nothing saturated -> per-wave critical-path bound with
//    ~3 waves/SIMD effective. Lever: more work per wave.
//  - pair_kernel: 4 m-tiles/wave (64 pairs), w2t B-frags shared 4-ways.
//  - gat_gather: 16-deep predicated unroll (deg~17 -> one volley).
//  - Everything else = round-12 (fp8 gather storage, fused alpha, CSR once).
//  - NOTE: no comment may end with a backslash (rounds 9/10 compile bug).
// ---------------------------------------------------------------------------

#define NEG_SLOPE 0.2f

typedef __bf16 bf16x8 __attribute__((ext_vector_type(8)));
typedef float  f32x4  __attribute__((ext_vector_type(4)));

static __device__ __forceinline__ float fp8_to_f32(unsigned b) {
  __hip_fp8_e4m3 t; t.__x = (__hip_fp8_storage_t)(b & 0xff);
  return (float)t;
}
static __device__ __forceinline__ unsigned char f32_to_fp8(float f) {
  __hip_fp8_e4m3 t(f); return (unsigned char)t.__x;
}
static __device__ __forceinline__ void fp8x4_to_f32(unsigned w, float* o) {
  o[0] = fp8_to_f32(w);
  o[1] = fp8_to_f32(w >> 8);
  o[2] = fp8_to_f32(w >> 16);
  o[3] = fp8_to_f32(w >> 24);
}

// --- weight preconvert/transpose to bf16 [NOUT][K] -------------------------
__global__ __launch_bounds__(256) void convw_kernel(
    const float* __restrict__ W1, const float* __restrict__ W2,
    const float* __restrict__ mw1, const float* __restrict__ mw2,
    __bf16* __restrict__ W1t, __bf16* __restrict__ W2t,
    __bf16* __restrict__ mw1t, __bf16* __restrict__ w2t)
{
  const int i = blockIdx.x * 256 + threadIdx.x;
  if (i < 16384) {
    const int nn = i >> 7, k = i & 127;
    W1t[i] = (__bf16)W1[k * 128 + nn];
    W2t[i] = (__bf16)W2[k * 128 + nn];
  }
  if (i < 32768) {
    const int j = i >> 7, k = i & 127;
    mw1t[i] = (__bf16)((j < 128) ? mw1[k * 128 + j]
                                 : mw1[(128 + k) * 128 + (j - 128)]);
  }
  if (i < 8192) {
    const int nn = i >> 7, k = i & 127;
    w2t[i] = (__bf16)mw2[k * 64 + nn];
  }
}

// --- node GEMM on MFMA: C8[n][NOUT] = fp8(A[n][128] @ Wt^T + fold) ---------
template<int NOUT, int HEADS, bool AF32, bool FOLDB>
__global__ __launch_bounds__(256) void nodegemm_kernel(
    const __bf16* __restrict__ A, const float* __restrict__ A32,
    const __bf16* __restrict__ Wt, unsigned char* __restrict__ C8,
    const float* __restrict__ asrc, const float* __restrict__ adst,
    float* __restrict__ as_out, float* __restrict__ ad_out,
    const float* __restrict__ vbias, int n)
{
  constexpr int NT = NOUT / 64;
  const int tid = threadIdx.x;
  const int wave = tid >> 6, lane = tid & 63;
  const int l16 = lane & 15;
  const int kl  = (lane >> 4) << 3;
  const int r4  = (lane >> 4) << 2;
  const int n0  = wave * (NOUT / 4);
  const int rowbase = blockIdx.x * 32;

  bf16x8 a[2][4];
  #pragma unroll
  for (int mt = 0; mt < 2; ++mt) {
    int row = rowbase + mt * 16 + l16;
    if (row >= n) row = n - 1;
    const size_t rb = (size_t)row * 128;
    #pragma unroll
    for (int ks = 0; ks < 4; ++ks) {
      if (AF32) {
        const float4 f0 = *(const float4*)&A32[rb + ks * 32 + kl];
        const float4 f1 = *(const float4*)&A32[rb + ks * 32 + kl + 4];
        bf16x8 t;
        t[0] = (__bf16)f0.x; t[1] = (__bf16)f0.y;
        t[2] = (__bf16)f0.z; t[3] = (__bf16)f0.w;
        t[4] = (__bf16)f1.x; t[5] = (__bf16)f1.y;
        t[6] = (__bf16)f1.z; t[7] = (__bf16)f1.w;
        a[mt][ks] = t;
      } else {
        a[mt][ks] = *(const bf16x8*)&A[rb + ks * 32 + kl];
      }
    }
  }
  f32x4 acc[2][NT];
  #pragma unroll
  for (int mt = 0; mt < 2; ++mt)
    #pragma unroll
    for (int nt = 0; nt < NT; ++nt) acc[mt][nt] = (f32x4){0.f, 0.f, 0.f, 0.f};

  #pragma unroll
  for (int ks = 0; ks < 4; ++ks) {
    #pragma unroll
    for (int nt = 0; nt < NT; ++nt) {
      const bf16x8 b =
          *(const bf16x8*)&Wt[(size_t)(n0 + nt * 16 + l16) * 128 + ks * 32 + kl];
      #pragma unroll
      for (int mt = 0; mt < 2; ++mt)
        acc[mt][nt] = __builtin_amdgcn_mfma_f32_16x16x32_bf16(
            a[mt][ks], b, acc[mt][nt], 0, 0, 0);
    }
  }

  // D layout: col = lane&15 (per 16-tile), row = (lane>>4)*4 + j   (m89)
  #pragma unroll
  for (int mt = 0; mt < 2; ++mt) {
    #pragma unroll
    for (int nt = 0; nt < NT; ++nt) {
      const int col = n0 + nt * 16 + l16;
      float vb = 0.f;
      if (FOLDB) vb = (col >= 128) ? vbias[col - 128] : 0.f;
      #pragma unroll
      for (int j = 0; j < 4; ++j) {
        const int row = rowbase + mt * 16 + r4 + j;
        if (row < n) C8[(size_t)row * NOUT + col] = f32_to_fp8(acc[mt][nt][j] + vb);
      }
    }
  }

  // fused alpha epilogue (from fp32 acc, pre-quantization)
  if (HEADS > 0) {
    float a_s[NT], a_d[NT];
    #pragma unroll
    for (int nt = 0; nt < NT; ++nt) {
      const int col = n0 + nt * 16 + l16;
      a_s[nt] = asrc[col]; a_d[nt] = adst[col];
    }
    #pragma unroll
    for (int mt = 0; mt < 2; ++mt) {
      #pragma unroll
      for (int j = 0; j < 4; ++j) {
        float ps = 0.f, pd = 0.f;
        #pragma unroll
        for (int nt = 0; nt < NT; ++nt) {
          ps += acc[mt][nt][j] * a_s[nt];
          pd += acc[mt][nt][j] * a_d[nt];
        }
        #pragma unroll
        for (int m = 1; m <= 8; m <<= 1) {   // reduce the 16-lane col group
          ps += __shfl_xor(ps, m); pd += __shfl_xor(pd, m);
        }
        const int row = rowbase + mt * 16 + r4 + j;
        if (l16 == 0 && row < n) {           // row<n also kills clamped dups
          if (HEADS == 4) {                  // wave's 32 cols == head `wave`
            as_out[row * 4 + wave] = ps;
            ad_out[row * 4 + wave] = pd;
          } else {                           // partial over 32 of 128 cols
            atomicAdd(&as_out[row], ps);
            atomicAdd(&ad_out[row], pd);
          }
        }
      }
    }
  }
}

// --- CSR build: histogram -> block scan -> scatter -------------------------
__global__ __launch_bounds__(256) void hist_kernel(
    const int* __restrict__ ei, int* __restrict__ deg, int E, int n)
{
  const int e = blockIdx.x * 256 + threadIdx.x;
  if (e >= E + n) return;
  const int d = (e < E) ? ei[E + e] : e - E;   // self-loops appended
  atomicAdd(&deg[d], 1);
}

__global__ __launch_bounds__(256) void scan1_kernel(
    const int* __restrict__ deg, int* __restrict__ part,
    int* __restrict__ bsum, int n)
{
  __shared__ int s[256];
  const int i = blockIdx.x * 256 + threadIdx.x;
  s[threadIdx.x] = (i < n) ? deg[i] : 0;
  __syncthreads();
  #pragma unroll
  for (int off = 1; off < 256; off <<= 1) {
    const int t = (threadIdx.x >= off) ? s[threadIdx.x - off] : 0;
    __syncthreads();
    s[threadIdx.x] += t;
    __syncthreads();
  }
  if (i < n) part[i] = s[threadIdx.x];
  if (threadIdx.x == 255) bsum[blockIdx.x] = s[255];
}

__global__ __launch_bounds__(256) void scan2_kernel(int* __restrict__ bsum, int nb)
{
  __shared__ int s[256];
  s[threadIdx.x] = (threadIdx.x < nb) ? bsum[threadIdx.x] : 0;
  __syncthreads();
  #pragma unroll
  for (int off = 1; off < 256; off <<= 1) {
    const int t = (threadIdx.x >= off) ? s[threadIdx.x - off] : 0;
    __syncthreads();
    s[threadIdx.x] += t;
    __syncthreads();
  }
  const int excl = (threadIdx.x == 0) ? 0 : s[threadIdx.x - 1];
  if (threadIdx.x < nb) bsum[threadIdx.x] = excl;
}

__global__ __launch_bounds__(256) void scan3_kernel(
    const int* __restrict__ part, const int* __restrict__ bsum,
    int* __restrict__ rowptr, int n)
{
  const int i = blockIdx.x * 256 + threadIdx.x;
  if (i < n) rowptr[i + 1] = part[i] + bsum[blockIdx.x];
  if (i == 0) rowptr[0] = 0;
}

__global__ __launch_bounds__(256) void fill_kernel(
    const int* __restrict__ ei, const int* __restrict__ rowptr,
    int* __restrict__ cur, int* __restrict__ csr_src, int E, int n)
{
  const int e = blockIdx.x * 256 + threadIdx.x;
  if (e >= E + n) return;
  int s, d;
  if (e < E) { s = ei[e]; d = ei[E + e]; }
  else       { s = e - E; d = s; }
  const int pos = rowptr[d] + atomicAdd(&cur[d], 1);
  csr_src[pos] = s;
}

// --- fused GAT aggregate: one wave per dst, 16-deep unroll, fp8 rows -------
template<int HEADS, bool DO_ELU>
__global__ __launch_bounds__(256) void gat_gather_kernel(
    const int* __restrict__ csr_src, const int* __restrict__ rowptr,
    const unsigned char* __restrict__ xw8,
    const float* __restrict__ as_, const float* __restrict__ ad_,
    const float* __restrict__ bias,
    __bf16* __restrict__ out, int n)
{
  const int d = blockIdx.x * 4 + (threadIdx.x >> 6);
  if (d >= n) return;
  const int lane = threadIdx.x & 63;
  const int c0 = lane * 2;
  constexpr int C = 128 / HEADS;
  const int head = c0 / C;
  const float ad_d = ad_[d * HEADS + head];
  const int r0 = rowptr[d], r1 = rowptr[d + 1];
  float accx = 0.f, accy = 0.f, den = 0.f;

  for (int i = r0; i < r1; i += 16) {
    int s[16];
    #pragma unroll
    for (int u = 0; u < 16; ++u)
      s[u] = csr_src[(i + u < r1) ? i + u : r1 - 1];
    float lg[16]; unsigned short pv[16];
    #pragma unroll
    for (int u = 0; u < 16; ++u) {         // 32 independent loads in flight
      lg[u] = as_[s[u] * HEADS + head];
      pv[u] = *(const unsigned short*)&xw8[(size_t)s[u] * 128 + c0];
    }
    #pragma unroll
    for (int u = 0; u < 16; ++u) {
      float l = lg[u] + ad_d;
      l = (l > 0.f) ? l : NEG_SLOPE * l;
      const float ex = (i + u < r1) ? __expf(l) : 0.f;
      accx += ex * fp8_to_f32(pv[u]);
      accy += ex * fp8_to_f32((unsigned)pv[u] >> 8);
      den  += ex;
    }
  }

  const float inv = 1.f / den;              // deg >= 1 (self-loop) -> no /0
  float rx = accx * inv + bias[c0];
  float ry = accy * inv + bias[c0 + 1];
  if (DO_ELU) {
    rx = rx > 0.f ? rx : expm1f(rx);
    ry = ry > 0.f ? ry : expm1f(ry);
  }
  union { __bf16 b[2]; unsigned u; } pk;
  pk.b[0] = (__bf16)rx; pk.b[1] = (__bf16)ry;
  *(unsigned*)&out[(size_t)d * 128 + c0] = pk.u;
}

// --- pair MLP: 4 m-tiles/wave (64 pairs), 256 pairs/block ------------------
// h1 = relu(uv[i,:128] + uv[j,128:]) (mb1 pre-folded into v-half) in regs
// -> MFMA GEMM2 bf16 (B-frag shared across 4 tiles) -> dot64 -> sigmoid.
__global__ __launch_bounds__(256) void pair_kernel(
    const unsigned char* __restrict__ uv8, const int* __restrict__ pairs,
    const __bf16* __restrict__ w2t, const float* __restrict__ mb2,
    const float* __restrict__ mw3, const float* __restrict__ mb3,
    float* __restrict__ out, int P)
{
  const int tid = threadIdx.x;
  const int wave = tid >> 6, lane = tid & 63;
  const int l16 = lane & 15;
  const int kl  = (lane >> 4) << 3;
  const int r4  = (lane >> 4) << 2;
  const int mbase = blockIdx.x * 256 + wave * 64;

  bf16x8 a[4][4];
  #pragma unroll
  for (int t = 0; t < 4; ++t) {
    int p = mbase + t * 16 + l16;
    if (p >= P) p = P - 1;
    const size_t ib = (size_t)pairs[p] * 256;
    const size_t jb = (size_t)pairs[P + p] * 256 + 128;
    uint2 du[4], dv[4];
    #pragma unroll
    for (int s = 0; s < 4; ++s) {          // 8 independent 8B loads in flight
      du[s] = *(const uint2*)&uv8[ib + s * 32 + kl];
      dv[s] = *(const uint2*)&uv8[jb + s * 32 + kl];
    }
    #pragma unroll
    for (int s = 0; s < 4; ++s) {
      float fu[8], fv[8];
      fp8x4_to_f32(du[s].x, fu); fp8x4_to_f32(du[s].y, fu + 4);
      fp8x4_to_f32(dv[s].x, fv); fp8x4_to_f32(dv[s].y, fv + 4);
      #pragma unroll
      for (int e = 0; e < 8; ++e)
        a[t][s][e] = (__bf16)fmaxf(fu[e] + fv[e], 0.f);
    }
  }

  f32x4 acc[4][4] = {};
  #pragma unroll
  for (int ks = 0; ks < 4; ++ks) {
    #pragma unroll
    for (int ni = 0; ni < 4; ++ni) {
      const bf16x8 b = *(const bf16x8*)&w2t[(size_t)(ni * 16 + l16) * 128 + ks * 32 + kl];
      #pragma unroll
      for (int t = 0; t < 4; ++t)          // B-frag reused by all 4 tiles
        acc[t][ni] = __builtin_amdgcn_mfma_f32_16x16x32_bf16(
            a[t][ks], b, acc[t][ni], 0, 0, 0);
    }
  }

  #pragma unroll
  for (int t = 0; t < 4; ++t) {
    float sum[4] = {0.f, 0.f, 0.f, 0.f};
    #pragma unroll
    for (int ni = 0; ni < 4; ++ni) {
      const int col = ni * 16 + l16;
      const float b2 = mb2[col];
      const float w3 = mw3[col];
      #pragma unroll
      for (int j = 0; j < 4; ++j)
        sum[j] += fmaxf(acc[t][ni][j] + b2, 0.f) * w3;
    }
    #pragma unroll
    for (int m = 1; m <= 8; m <<= 1) {
      #pragma unroll
      for (int j = 0; j < 4; ++j) sum[j] += __shfl_xor(sum[j], m);
    }
    if (l16 == 0) {
      const int p0 = mbase + t * 16 + r4;
      const float b3 = mb3[0];
      float4 o;
      o.x = 1.f / (1.f + __expf(-(sum[0] + b3)));
      o.y = 1.f / (1.f + __expf(-(sum[1] + b3)));
      o.z = 1.f / (1.f + __expf(-(sum[2] + b3)));
      o.w = 1.f / (1.f + __expf(-(sum[3] + b3)));
      if (p0 + 3 < P) {
        *(float4*)&out[p0] = o;
      } else {
        if (p0     < P) out[p0]     = o.x;
        if (p0 + 1 < P) out[p0 + 1] = o.y;
        if (p0 + 2 < P) out[p0 + 2] = o.z;
        if (p0 + 3 < P) out[p0 + 3] = o.w;
      }
    }
  }
}

// ---------------------------------------------------------------------------
extern "C" void kernel_launch(void* const* d_in, const int* in_sizes, int n_in,
                              void* d_out, int out_size, void* d_ws, size_t ws_size,
                              hipStream_t stream)
{
  const float* x   = (const float*)d_in[0];
  const int*   ei  = (const int*)d_in[1];
  const int*   ep  = (const int*)d_in[2];
  const float* W1  = (const float*)d_in[3];
  const float* as1 = (const float*)d_in[4];
  const float* ad1 = (const float*)d_in[5];
  const float* b1  = (const float*)d_in[6];
  const float* W2  = (const float*)d_in[7];
  const float* as2 = (const float*)d_in[8];
  const float* ad2 = (const float*)d_in[9];
  const float* b2  = (const float*)d_in[10];
  const float* mw1 = (const float*)d_in[11];
  const float* mb1 = (const float*)d_in[12];
  const float* mw2 = (const float*)d_in[13];
  const float* mb2 = (const float*)d_in[14];
  const float* mw3 = (const float*)d_in[15];
  const float* mb3 = (const float*)d_in[16];

  const int N = in_sizes[0] / 128;
  const int E = in_sizes[1] / 2;
  const int P = in_sizes[2] / 2;
  const int EN = E + N;

  // ---- workspace carve-up (~55 MB) ----
  __bf16* z_bf  = (__bf16*)d_ws;                              // N*128 bf16
  __bf16* h_bf  = z_bf + (size_t)N * 128;                     // N*128 bf16
  unsigned char* xw8 = (unsigned char*)(h_bf + (size_t)N * 128);  // N*128 fp8
  unsigned char* uv8 = xw8 + (size_t)N * 128;                 // N*256 fp8
  __bf16* W1t   = (__bf16*)(uv8 + (size_t)N * 256);           // 128*128
  __bf16* W2t   = W1t + 16384;                                // 128*128
  __bf16* mw1t  = W2t + 16384;                                // 256*128
  __bf16* w2t   = mw1t + 32768;                               // 64*128
  float*  as_   = (float*)(w2t + 8192);                       // N*4 (layer1)
  float*  ad_   = as_ + (size_t)N * 4;                        // N*4
  int*    deg   = (int*)(ad_ + (size_t)N * 4);                // N (zero region)
  int*    cur   = deg + N;                                    // N (zeroed)
  float*  as2v  = (float*)(cur + N);                          // N (zeroed)
  float*  ad2v  = as2v + N;                                   // N (zeroed end)
  int* part     = (int*)(ad2v + N);                           // N
  int* bsum     = part + N;                                   // 256
  int* rowptr   = bsum + 256;                                 // N+1
  int* csr_src  = rowptr + (N + 1);                           // E+N
  float* out    = (float*)d_out;

  const int gEN = (EN + 255) / 256;
  const int nb  = (N + 255) / 256;           // 196 <= 256 (single-block scan2)
  const int gNG = (N + 31) / 32;

  // ---- CSR build (once; both layers share the graph) + zero accumulators --
  (void)hipMemsetAsync(deg, 0, (size_t)4 * N * sizeof(int), stream);  // deg,cur,as2v,ad2v
  hist_kernel <<<gEN, 256, 0, stream>>>(ei, deg, E, N);
  scan1_kernel<<<nb, 256, 0, stream>>>(deg, part, bsum, N);
  scan2_kernel<<<1, 256, 0, stream>>>(bsum, nb);
  scan3_kernel<<<nb, 256, 0, stream>>>(part, bsum, rowptr, N);
  fill_kernel <<<gEN, 256, 0, stream>>>(ei, rowptr, cur, csr_src, E, N);
  convw_kernel<<<128, 256, 0, stream>>>(W1, W2, mw1, mw2, W1t, W2t, mw1t, w2t);

  // ---- layer 1 (heads=4): x -> xw8 (+as_/ad_ fused) -> h_bf ----
  nodegemm_kernel<128, 4, true, false><<<gNG, 256, 0, stream>>>(
      nullptr, x, W1t, xw8, as1, ad1, as_, ad_, nullptr, N);
  gat_gather_kernel<4, true><<<(N + 3) / 4, 256, 0, stream>>>(
      csr_src, rowptr, xw8, as_, ad_, b1, h_bf, N);

  // ---- layer 2 (heads=1): h_bf -> xw8 (+as2v/ad2v fused) -> z_bf ----
  nodegemm_kernel<128, 1, false, false><<<gNG, 256, 0, stream>>>(
      h_bf, nullptr, W2t, xw8, as2, ad2, as2v, ad2v, nullptr, N);
  gat_gather_kernel<1, false><<<(N + 3) / 4, 256, 0, stream>>>(
      csr_src, rowptr, xw8, as2v, ad2v, b2, z_bf, N);

  // ---- uv = fp8(z @ [mw1_u | mw1_v] + mb1-fold on v-half) ----
  nodegemm_kernel<256, 0, false, true><<<gNG, 256, 0, stream>>>(
      z_bf, nullptr, mw1t, uv8, nullptr, nullptr, nullptr, nullptr, mb1, N);

  // ---- pair MLP (4-tile, fp8 gather, bf16 MFMA) ----
  pair_kernel<<<(P + 255) / 256, 256, 0, stream>>>(
      uv8, ep, w2t, mb2, mw3, mb3, out, P);
}